// Round 3
// baseline (112.997 us; speedup 1.0000x reference)
//
#include <hip/hip_runtime.h>
#include <math.h>

#define NUM_EMB 8192
#define DIM     4
#define NTOK    32768                 // B*L = 8*4096
#define NCHUNK  16
#define CHUNK   (NUM_EMB / NCHUNK)    // 512 embeddings per chunk
#define TPB     256
#define TPT     2                     // tokens per thread
#define TOKBLK  (TPB * TPT)           // 512 tokens per block
#define NTB     (NTOK / TOKBLK)       // 64 token-blocks
#define NMB     (NTOK / TPB)          // 128 merge blocks

// Constant address space: uniform-index loads compile to s_load_* (scalar
// pipe), keeping the vector memory path and LDS completely idle.
#define CONSTANT __attribute__((address_space(4)))
typedef const float CONSTANT* cfloat_p;

// Kernel A: per (token, chunk) partial argmax of dot(x,e).
// grid = (64, 16) = 1024 blocks = 4096 waves = 4 waves/SIMD.
// Embeddings are wave-uniform -> s_load into SGPRs (no LDS, no VMEM in the
// hot loop); each VALU fma reads one SGPR operand (legal). Per iteration:
// 2 dots (8 fma-class) + 2 cmp + 4 cndmask + 1 add = 15 VALU, 0 LDS.
__global__ __launch_bounds__(TPB, 4) void vq_scan(
    const float4* __restrict__ x,
    const float*  __restrict__ emb,
    float* __restrict__ part_best,
    int*   __restrict__ part_idx) {

    const int chunk = blockIdx.y;
    const int ebase = chunk * CHUNK;
    cfloat_p ef = (cfloat_p)(emb + (size_t)ebase * DIM);

    const int t0 = blockIdx.x * TOKBLK + threadIdx.x;  // coalesced
    const int t1 = t0 + TPB;                           // coalesced
    const float4 x0 = x[t0];
    const float4 x1 = x[t1];

    float best0 = -INFINITY, best1 = -INFINITY;
    int   bi0 = 0, bi1 = 0;
    int   nv = 0;   // embedding counter; both tokens' selects reuse it

    #pragma unroll 8
    for (int n = 0; n < CHUNK; ++n) {
        const float ex = ef[4 * n + 0];   // adjacent s_load_dword merge into
        const float ey = ef[4 * n + 1];   // s_load_dwordx16 under unroll
        const float ez = ef[4 * n + 2];
        const float ew = ef[4 * n + 3];
        float d0 = fmaf(x0.w, ew, fmaf(x0.z, ez, fmaf(x0.y, ey, x0.x * ex)));
        float d1 = fmaf(x1.w, ew, fmaf(x1.z, ez, fmaf(x1.y, ey, x1.x * ex)));
        bool c0 = d0 > best0;             // strict > : first-max tie-break
        bool c1 = d1 > best1;
        bi0   = c0 ? nv : bi0;
        bi1   = c1 ? nv : bi1;
        best0 = c0 ? d0 : best0;
        best1 = c1 ? d1 : best1;
        ++nv;
    }

    part_best[chunk * NTOK + t0] = best0;
    part_idx [chunk * NTOK + t0] = ebase + bi0;
    part_best[chunk * NTOK + t1] = best1;
    part_idx [chunk * NTOK + t1] = ebase + bi1;
}

// Kernel B: merge 16 partials/token (ascending chunk order -> first-max
// tie-break), gather e, sum |x-e|, block-reduce, one atomicAdd per block.
__global__ __launch_bounds__(TPB) void vq_merge(
    const float4* __restrict__ x,
    const float4* __restrict__ emb,
    const float* __restrict__ part_best,
    const int*   __restrict__ part_idx,
    float* __restrict__ out) {

    const int tok = blockIdx.x * TPB + threadIdx.x;

    float best = -INFINITY;
    int   bi   = 0;
    #pragma unroll
    for (int c = 0; c < NCHUNK; ++c) {
        float b = part_best[c * NTOK + tok];
        int   i = part_idx [c * NTOK + tok];
        if (b > best) { best = b; bi = i; }
    }

    const float4 e  = emb[bi];
    const float4 xv = x[tok];
    float s = fabsf(xv.x - e.x) + fabsf(xv.y - e.y)
            + fabsf(xv.z - e.z) + fabsf(xv.w - e.w);

    #pragma unroll
    for (int off = 32; off > 0; off >>= 1)
        s += __shfl_down(s, off, 64);

    __shared__ float ws[TPB / 64];
    if ((threadIdx.x & 63) == 0) ws[threadIdx.x >> 6] = s;
    __syncthreads();

    if (threadIdx.x == 0) {
        float t = ws[0] + ws[1] + ws[2] + ws[3];
        // loss = (reg + embedding) = 2 * sum|x-e| / (NTOK*DIM)
        atomicAdd(out, t * (2.0f / (float)(NTOK * DIM)));
    }
}

extern "C" void kernel_launch(void* const* d_in, const int* in_sizes, int n_in,
                              void* d_out, int out_size, void* d_ws, size_t ws_size,
                              hipStream_t stream) {
    const float4* x4  = (const float4*)d_in[0];   // [8,4096,4] fp32
    const float*  emb = (const float*)d_in[1];    // [8192,4]   fp32
    float* out = (float*)d_out;

    // ws layout: part_best (2 MB) | part_idx (2 MB)
    float* part_best = (float*)d_ws;
    int*   part_idx  = (int*)((char*)d_ws + (size_t)NCHUNK * NTOK * sizeof(float));

    // d_out poisoned 0xAA before every launch; zero it for the atomics.
    hipMemsetAsync(d_out, 0, sizeof(float), stream);

    dim3 g1(NTB, NCHUNK);
    vq_scan <<<g1,  TPB, 0, stream>>>(x4, emb, part_best, part_idx);
    vq_merge<<<NMB, TPB, 0, stream>>>(x4, (const float4*)emb, part_best, part_idx, out);
}

// Round 4
// 106.916 us; speedup vs baseline: 1.0569x; 1.0569x over previous
//
#include <hip/hip_runtime.h>
#include <math.h>

#define NUM_EMB 8192
#define DIM     4
#define NTOK    32768                 // B*L = 8*4096
#define NCHUNK  32
#define CHUNK   (NUM_EMB / NCHUNK)    // 256 embeddings per chunk
#define BATCH   8
#define NBATCH  (CHUNK / BATCH)       // 32 batches per chunk
#define TPB     256
#define TPT     2                     // tokens per thread
#define TOKBLK  (TPB * TPT)           // 512 tokens per block
#define NTB     (NTOK / TOKBLK)       // 64 token-blocks
#define NMB     (NTOK / TPB)          // 128 merge blocks

// Constant address space: wave-uniform loads -> s_load (scalar pipe only).
#define CONSTANT __attribute__((address_space(4)))
typedef const float CONSTANT* cfloat_p;

// identical fmaf chain in BOTH kernels -> bitwise-equal dots (exact re-find)
__device__ __forceinline__ float dot4(const float4& a,
                                      float ex, float ey, float ez, float ew) {
    return fmaf(a.w, ew, fmaf(a.z, ez, fmaf(a.y, ey, a.x * ex)));
}

// Kernel A: per (token, chunk) partial VALUE-max of dot(x,e), tracking only
// the winning 8-embedding BATCH id (index resolved later by exact re-scan).
// grid = (64, 32) = 2048 blocks = 8192 waves = 8 waves/SIMD.
// Per batch (16 pairs): 64 fma + 14 max + 6 select + 1 add ~= 5.3 inst/pair.
__global__ __launch_bounds__(TPB, 8) void vq_scan(
    const float4* __restrict__ x,
    const float*  __restrict__ emb,
    float* __restrict__ part_best,
    int*   __restrict__ part_batch,
    unsigned* __restrict__ counter) {

    if (blockIdx.x == 0 && blockIdx.y == 0 && threadIdx.x == 0)
        *counter = 0;   // visible to vq_merge at dispatch boundary

    const int chunk = blockIdx.y;
    cfloat_p ef = (cfloat_p)(emb + (size_t)chunk * CHUNK * DIM);

    const int t0 = blockIdx.x * TOKBLK + threadIdx.x;  // coalesced
    const int t1 = t0 + TPB;                           // coalesced
    const float4 x0 = x[t0];
    const float4 x1 = x[t1];

    float best0 = -INFINITY, best1 = -INFINITY;
    int   bb0 = 0, bb1 = 0;
    int   nb  = 0;    // batch counter in a register (not foldable: rolled loop)

    #pragma unroll 2
    for (int b = 0; b < NBATCH; ++b) {
        float d0[BATCH], d1[BATCH];
        #pragma unroll
        for (int j = 0; j < BATCH; ++j) {
            const float ex = ef[(b * BATCH + j) * 4 + 0];
            const float ey = ef[(b * BATCH + j) * 4 + 1];
            const float ez = ef[(b * BATCH + j) * 4 + 2];
            const float ew = ef[(b * BATCH + j) * 4 + 3];
            d0[j] = dot4(x0, ex, ey, ez, ew);
            d1[j] = dot4(x1, ex, ey, ez, ew);
        }
        // value-only max over the batch (compiler forms v_max3_f32)
        float m0 = fmaxf(fmaxf(fmaxf(d0[0], d0[1]), fmaxf(d0[2], d0[3])),
                         fmaxf(fmaxf(d0[4], d0[5]), fmaxf(d0[6], d0[7])));
        float m1 = fmaxf(fmaxf(fmaxf(d1[0], d1[1]), fmaxf(d1[2], d1[3])),
                         fmaxf(fmaxf(d1[4], d1[5]), fmaxf(d1[6], d1[7])));
        bool c0 = m0 > best0;       // strict > : earliest batch wins ties
        bool c1 = m1 > best1;
        bb0   = c0 ? nb : bb0;
        bb1   = c1 ? nb : bb1;
        best0 = c0 ? m0 : best0;
        best1 = c1 ? m1 : best1;
        ++nb;
    }

    part_best [chunk * NTOK + t0] = best0;
    part_batch[chunk * NTOK + t0] = chunk * NBATCH + bb0;
    part_best [chunk * NTOK + t1] = best1;
    part_batch[chunk * NTOK + t1] = chunk * NBATCH + bb1;
}

// Kernel B: merge 32 partials/token (ascending chunk order -> first-max
// tie-break), exact re-scan of the winning batch to recover e, sum |x-e|,
// block-reduce, last-block-final reduction (no extra kernel, no memset).
__global__ __launch_bounds__(TPB) void vq_merge(
    const float4* __restrict__ x,
    const float4* __restrict__ emb,
    const float* __restrict__ part_best,
    const int*   __restrict__ part_batch,
    float* __restrict__ blocksum,
    unsigned* __restrict__ counter,
    float* __restrict__ out) {

    const int tok = blockIdx.x * TPB + threadIdx.x;

    float best = -INFINITY;
    int   bb   = 0;
    #pragma unroll
    for (int c = 0; c < NCHUNK; ++c) {
        float v = part_best [c * NTOK + tok];
        int   i = part_batch[c * NTOK + tok];
        bool  cc = v > best;
        best = cc ? v : best;
        bb   = cc ? i : bb;
    }

    const float4 xv = x[tok];

    // exact re-scan of the 8-embedding winning batch; descending j so the
    // FIRST j with dot == best wins (jnp.argmax tie-break).
    float4 cand[BATCH];
    float  d[BATCH];
    #pragma unroll
    for (int j = 0; j < BATCH; ++j) {
        cand[j] = emb[bb * BATCH + j];
        d[j] = dot4(xv, cand[j].x, cand[j].y, cand[j].z, cand[j].w);
    }
    float4 e = cand[BATCH - 1];
    #pragma unroll
    for (int j = BATCH - 1; j >= 0; --j)
        if (d[j] == best) e = cand[j];

    float s = fabsf(xv.x - e.x) + fabsf(xv.y - e.y)
            + fabsf(xv.z - e.z) + fabsf(xv.w - e.w);

    #pragma unroll
    for (int off = 32; off > 0; off >>= 1)
        s += __shfl_down(s, off, 64);

    __shared__ float ws[TPB / 64];
    __shared__ bool  last;
    if ((threadIdx.x & 63) == 0) ws[threadIdx.x >> 6] = s;
    __syncthreads();

    if (threadIdx.x == 0) {
        blocksum[blockIdx.x] = ws[0] + ws[1] + ws[2] + ws[3];
        __threadfence();   // make blocksum visible device-wide
        unsigned old = __hip_atomic_fetch_add(counter, 1u, __ATOMIC_ACQ_REL,
                                              __HIP_MEMORY_SCOPE_AGENT);
        last = (old == NMB - 1);
    }
    __syncthreads();

    if (last) {
        float t = 0.f;
        if (threadIdx.x < NMB)
            t = ((volatile float*)blocksum)[threadIdx.x];
        #pragma unroll
        for (int off = 32; off > 0; off >>= 1)
            t += __shfl_down(t, off, 64);
        if ((threadIdx.x & 63) == 0) ws[threadIdx.x >> 6] = t;
        __syncthreads();
        if (threadIdx.x == 0)
            out[0] = (ws[0] + ws[1]) * (2.0f / (float)(NTOK * DIM));
    }
}

extern "C" void kernel_launch(void* const* d_in, const int* in_sizes, int n_in,
                              void* d_out, int out_size, void* d_ws, size_t ws_size,
                              hipStream_t stream) {
    const float4* x4  = (const float4*)d_in[0];   // [8,4096,4] fp32
    const float*  emb = (const float*)d_in[1];    // [8192,4]   fp32
    float* out = (float*)d_out;

    // ws: part_best (4 MB) | part_batch (4 MB) | blocksum (512 B) | counter
    char* w = (char*)d_ws;
    float*    part_best  = (float*)w;
    int*      part_batch = (int*)(w + (size_t)NCHUNK * NTOK * 4);
    float*    blocksum   = (float*)(w + (size_t)2 * NCHUNK * NTOK * 4);
    unsigned* counter    = (unsigned*)(w + (size_t)2 * NCHUNK * NTOK * 4 + NMB * 4);

    dim3 g1(NTB, NCHUNK);
    vq_scan <<<g1,  TPB, 0, stream>>>((const float4*)x4, emb,
                                      part_best, part_batch, counter);
    vq_merge<<<NMB, TPB, 0, stream>>>(x4, (const float4*)emb,
                                      part_best, part_batch,
                                      blocksum, counter, out);
}